// Round 1
// 272.539 us; speedup vs baseline: 1.0652x; 1.0652x over previous
//
#include <hip/hip_runtime.h>

// Orient_Conv: 3x3 orientation-gated conv, 4 orientations + per-pixel argmax.
// B=4, CIN=COUT=32, H=W=128, pad=1.
//
// Gate identity (C=cos(wr), S=sin(wr), r0=cos(th), r1=sin(th)):
//   u = C*r0+S*r1, vv = C*r1-S*r0
//   gates: o0=relu(u), o1=relu(vv), o2=relu(-u), o3=relu(-vv)
//   products: t0=f*relu(u), t1=f*relu(vv), t2 = t0 - f*u (=f*relu(-u)),
//             t3 = t1 - f*vv  -> 14-op core, packed 2 px/v2f = 8 VALU/elem.
// Rotated weights at tap (i,j): w0=w[i][j], w1=w[2-j][i], w2=w[2-i][2-j],
//   w3=w[j][2-i].
//
// R11 = R10 + hoisted per-cc weight loads. Diagnosis: R10 at 241 us has
// ~11k issue-slots/thread ~= 73 us of pure issue -> ~30% issue util;
// the per-(cc,tap) VMEM weight loads (use distance ~15 insts, L2 latency
// 200-400 cyc) stall each wave, and ~13 resident waves/CU can't cover it
// (VGPR=48 shows the compiler kept a just-in-time schedule, no prefetch
// depth). Fix: batch all 18 weight loads (54 floats) at the top of each
// cc body -> 18-deep MLP, one progressive vmcnt chain per cc. VGPR rises
// past the 64-reg 4-block/CU cliff (-> 2 blocks/CU, 16 waves) which is
// acceptable: measured residency was already ~13 waves/CU; per-wave MLP
// replaces TLP. Weight table [cc][tap][oc][8] (coalesced 1KB wave loads),
// 2 imm anchors keep all 18 loads within signed-13-bit imm offsets.

typedef float v2f __attribute__((ext_vector_type(2)));

#define B_    4
#define CIN_  32
#define COUT_ 32
#define H_    128
#define W_    128
#define HW_   (H_ * W_)
#define OUTSZ_ (B_ * COUT_ * H_ * W_)

// tab layout: [cc][tap][oc][8] = {C,S,w0,w1,w2,w3,0,0}; 294912 B
__global__ __launch_bounds__(256)
void build_wtab(const float* __restrict__ w, const float* __restrict__ wr,
                float* __restrict__ tab)
{
    int idx = blockIdx.x * 256 + threadIdx.x;   // ((cc*9+tap)<<5)|oc
    if (idx >= CIN_ * 9 * COUT_) return;        // 9216
    int oc  = idx & 31;
    int t2  = idx >> 5;
    int tap = t2 % 9;
    int cc  = t2 / 9;
    int i = tap / 3, j = tap - i * 3;
    int base = (oc * CIN_ + cc) * 9;
    float w0 = w[base + i * 3 + j];
    float w1 = w[base + (2 - j) * 3 + i];
    float w2 = w[base + (2 - i) * 3 + (2 - j)];
    float w3 = w[base + j * 3 + (2 - i)];
    float S, C;
    sincosf(wr[base + i * 3 + j], &S, &C);
    float* dst = tab + (size_t)idx * 8;
    dst[0] = C;  dst[1] = S;
    dst[2] = w0; dst[3] = w1;
    dst[4] = w2; dst[5] = w3;
    dst[6] = 0.0f; dst[7] = 0.0f;
}

#define NC_    8                      // channels staged per barrier-pair
#define NG_    (CIN_ / NC_)           // 4 groups
#define ROWF_  68                     // floats per row = 34 pairs x 2
#define CLSTR_ (3 * ROWF_)            // 204 floats per staged channel
#define USED_  (NC_ * CLSTR_)         // 1632 slots per plane
#define PLANE_ 1636                   // plane stride (pad; 1636%32=4)

__global__ __launch_bounds__(512, 4)
void orient_conv_kernel(const float* __restrict__ f,
                        const float* __restrict__ r0,
                        const float* __restrict__ r1,
                        const float* __restrict__ tab,
                        float* __restrict__ out)
{
    // planes: 0=f, PLANE_=r0, 2*PLANE_=r1. Within plane:
    // [cl(8)][row(3)][pairslot(68)] ; pairslot = c01*2 + s holds col c01+32*s
    __shared__ float sm[3 * PLANE_];   // 19632 B

    const int tid   = threadIdx.x;
    const int oc    = tid & 31;
    const int pxg   = tid >> 5;            // 0..15
    const int p     = pxg << 1;            // even pair index 0..30
    const int bid   = blockIdx.x;          // 0..1023
    const int b     = bid >> 8;
    const int rem   = bid & 255;
    const int h     = rem >> 1;
    const int wbase = (rem & 1) << 6;      // 0 or 64

    // ---- staging descriptors: rounds 0..2 always valid, round 3 tid<96 ----
    int      goff[4], sidx[4];
    unsigned msk[4];
#pragma unroll
    for (int k = 0; k < 4; ++k) {
        int s = tid + (k << 9);
        if (s < USED_) {
            int cl  = s / CLSTR_;
            int r2  = s - cl * CLSTR_;
            int row = r2 / ROWF_;
            int q2  = r2 - row * ROWF_;     // 0..67
            int col = (q2 >> 1) + ((q2 & 1) << 5);   // c01 + 32*s -> 0..65
            int gh = h + row - 1;
            int gw = wbase + col - 1;
            bool ok = ((unsigned)gh < (unsigned)H_) & ((unsigned)gw < (unsigned)W_);
            goff[k] = ok ? (cl * HW_ + gh * W_ + gw) : 0;
            msk[k]  = ok ? 0xFFFFFFFFu : 0u;
            sidx[k] = s;
        } else { goff[k] = 0; msk[k] = 0u; sidx[k] = USED_; }  // pad slot
    }
    const bool have3 = (tid + 1536) < USED_;   // tid < 96
    const int chanBase = b * (CIN_ * HW_);

    v2f acc[2][4];                     // [pair q][orient]; elems = px, px+32
#pragma unroll
    for (int q = 0; q < 2; ++q)
#pragma unroll
        for (int o = 0; o < 4; ++o) acc[q][o] = (v2f)(0.0f);

    // ---- prefetch group 0 ----
    float tF[4], tA[4], tB[4];
    {
        const float* fb = f  + chanBase;
        const float* ab = r0 + chanBase;
        const float* bb = r1 + chanBase;
#pragma unroll
        for (int k = 0; k < 3; ++k) {
            tF[k] = fb[goff[k]]; tA[k] = ab[goff[k]]; tB[k] = bb[goff[k]];
        }
        if (have3) { tF[3] = fb[goff[3]]; tA[3] = ab[goff[3]]; tB[3] = bb[goff[3]]; }
    }

#pragma unroll 1
    for (int g = 0; g < NG_; ++g) {
        __syncthreads();   // all waves done reading LDS of group g-1
#pragma unroll
        for (int k = 0; k < 3; ++k) {
            sm[             sidx[k]] = __uint_as_float(__float_as_uint(tF[k]) & msk[k]);
            sm[PLANE_     + sidx[k]] = __uint_as_float(__float_as_uint(tA[k]) & msk[k]);
            sm[2 * PLANE_ + sidx[k]] = __uint_as_float(__float_as_uint(tB[k]) & msk[k]);
        }
        if (have3) {
            sm[             sidx[3]] = __uint_as_float(__float_as_uint(tF[3]) & msk[3]);
            sm[PLANE_     + sidx[3]] = __uint_as_float(__float_as_uint(tA[3]) & msk[3]);
            sm[2 * PLANE_ + sidx[3]] = __uint_as_float(__float_as_uint(tB[3]) & msk[3]);
        }
        __syncthreads();

        // ---- prefetch group g+1 (in flight during compute below) ----
        if (g + 1 < NG_) {
            const int gb = chanBase + (g + 1) * (NC_ * HW_);
            const float* fb = f  + gb;
            const float* ab = r0 + gb;
            const float* bb = r1 + gb;
#pragma unroll
            for (int k = 0; k < 3; ++k) {
                tF[k] = fb[goff[k]]; tA[k] = ab[goff[k]]; tB[k] = bb[goff[k]];
            }
            if (have3) { tF[3] = fb[goff[3]]; tA[3] = ab[goff[3]]; tB[3] = bb[goff[3]]; }
        }

        // ---- compute the NC_ staged channels ----
#pragma unroll 1
        for (int cl = 0; cl < NC_; ++cl) {
            const int cc = g * NC_ + cl;
            // imm-offset anchors (taps 2 and 6): all 18 weight loads within
            // signed-13-bit global imm offsets
            const float* wb0 = tab + (size_t)(((cc * 9 + 2) << 5) | oc) * 8;
            const float* wb1 = wb0 + 4 * 256;

            // ---- R11: batch ALL weight loads for this cc up front ----
            // 18 loads issued back-to-back -> 18-deep MLP, 300+ cycle
            // issue-to-use distance for taps 1..8 (progressive vmcnt).
            float4 W4s[9];
            float2 W2s[9];
#pragma unroll
            for (int t = 0; t < 9; ++t) {
                const float* wp = (t < 5) ? (wb0 + (t - 2) * 256)
                                          : (wb1 + (t - 6) * 256);
                W4s[t] = *reinterpret_cast<const float4*>(wp);
                W2s[t] = *reinterpret_cast<const float2*>(wp + 4);
            }

#pragma unroll
            for (int i = 0; i < 3; ++i) {
                const int bi = cl * CLSTR_ + i * ROWF_ + (p << 1);
                float4 fA = *reinterpret_cast<const float4*>(&sm[bi]);
                float4 fB = *reinterpret_cast<const float4*>(&sm[bi + 4]);
                float4 aA = *reinterpret_cast<const float4*>(&sm[PLANE_ + bi]);
                float4 aB = *reinterpret_cast<const float4*>(&sm[PLANE_ + bi + 4]);
                float4 bA = *reinterpret_cast<const float4*>(&sm[2 * PLANE_ + bi]);
                float4 bB = *reinterpret_cast<const float4*>(&sm[2 * PLANE_ + bi + 4]);
                v2f fP[4]  = {{fA.x, fA.y}, {fA.z, fA.w}, {fB.x, fB.y}, {fB.z, fB.w}};
                v2f aP[4]  = {{aA.x, aA.y}, {aA.z, aA.w}, {aB.x, aB.y}, {aB.z, aB.w}};
                v2f bP[4]  = {{bA.x, bA.y}, {bA.z, bA.w}, {bB.x, bB.y}, {bB.z, bB.w}};
#pragma unroll
                for (int j = 0; j < 3; ++j) {
                    const int tap = i * 3 + j;
                    float4 W4 = W4s[tap];
                    float2 W2 = W2s[tap];
                    v2f C2  = {W4.x, W4.x};
                    v2f S2  = {W4.y, W4.y};
                    v2f w02 = {W4.z, W4.z};
                    v2f w12 = {W4.w, W4.w};
                    v2f w22 = {W2.x, W2.x};
                    v2f w32 = {W2.y, W2.y};
#pragma unroll
                    for (int q = 0; q < 2; ++q) {
                        v2f fv  = fP[q + j];
                        v2f r0v = aP[q + j];
                        v2f r1v = bP[q + j];
                        v2f m1 = S2 * r1v;
                        v2f u  = __builtin_elementwise_fma(C2, r0v, m1);
                        v2f m2 = S2 * r0v;
                        v2f vv = __builtin_elementwise_fma(C2, r1v, -m2);
                        v2f g0 = __builtin_elementwise_max(u,  (v2f)(0.0f));
                        v2f g1 = __builtin_elementwise_max(vv, (v2f)(0.0f));
                        v2f t0 = fv * g0;
                        v2f t1 = fv * g1;
                        v2f t2 = __builtin_elementwise_fma(fv, -u,  t0);  // f*relu(-u)
                        v2f t3 = __builtin_elementwise_fma(fv, -vv, t1);  // f*relu(-vv)
                        acc[q][0] = __builtin_elementwise_fma(t0, w02, acc[q][0]);
                        acc[q][1] = __builtin_elementwise_fma(t1, w12, acc[q][1]);
                        acc[q][2] = __builtin_elementwise_fma(t2, w22, acc[q][2]);
                        acc[q][3] = __builtin_elementwise_fma(t3, w32, acc[q][3]);
                    }
                }
            }
        }
    }

    // ---- epilogue: max/argmax over orientations (first-max tie-break) ----
    const float cosv[4] = {1.0f, -4.37113883e-08f, -1.0f, 1.19248806e-08f};
    const float sinv[4] = {0.0f, 1.0f, -8.74227766e-08f, -1.0f};
#pragma unroll
    for (int q = 0; q < 2; ++q) {
#pragma unroll
        for (int k = 0; k < 2; ++k) {
            int wcol = wbase + p + q + (k << 5);
            float a0 = acc[q][0][k], a1 = acc[q][1][k];
            float a2 = acc[q][2][k], a3 = acc[q][3][k];
            float best = a0; int bi = 0;
            if (a1 > best) { best = a1; bi = 1; }
            if (a2 > best) { best = a2; bi = 2; }
            if (a3 > best) { best = a3; bi = 3; }
            size_t o = ((size_t)(b * COUT_ + oc) * H_ + h) * W_ + wcol;
            out[o]              = best;
            out[o + OUTSZ_]     = cosv[bi];
            out[o + 2 * OUTSZ_] = sinv[bi];
        }
    }
}

extern "C" void kernel_launch(void* const* d_in, const int* in_sizes, int n_in,
                              void* d_out, int out_size, void* d_ws, size_t ws_size,
                              hipStream_t stream)
{
    const float* f  = (const float*)d_in[0];
    const float* r0 = (const float*)d_in[1];
    const float* r1 = (const float*)d_in[2];
    const float* w  = (const float*)d_in[3];
    const float* wr = (const float*)d_in[4];
    float* out = (float*)d_out;
    float* tab = (float*)d_ws;    // 294912 B

    build_wtab<<<dim3(36), dim3(256), 0, stream>>>(w, wr, tab);
    orient_conv_kernel<<<dim3(B_ * H_ * 2), dim3(512), 0, stream>>>(
        f, r0, r1, tab, out);
}

// Round 2
// 270.325 us; speedup vs baseline: 1.0739x; 1.0082x over previous
//
#include <hip/hip_runtime.h>

// Orient_Conv: 3x3 orientation-gated conv, 4 orientations + per-pixel argmax.
// B=4, CIN=COUT=32, H=W=128, pad=1.
//
// Gate identity (C=cos(wr), S=sin(wr), r0=cos(th), r1=sin(th)):
//   u = C*r0+S*r1, vv = C*r1-S*r0
//   gates: o0=relu(u), o1=relu(vv), o2=relu(-u), o3=relu(-vv)
//   products: t0=f*relu(u), t1=f*relu(vv), t2 = t0 - f*u (=f*relu(-u)),
//             t3 = t1 - f*vv  -> 14-op packed core, 2 px/v2f.
// Rotated weights at tap (i,j): w0=w[i][j], w1=w[2-j][i], w2=w[2-i][2-j],
//   w3=w[j][2-i].
//
// R12 = R11 + scheduler-proof weight pipelining. R11 post-mortem: VGPR
// stayed at 64 (the 8-wave/SIMD cliff) -> regalloc SANK the 18 hoisted
// weight loads back toward uses; prefetch depth collapsed, gain was only
// 241->222 us. Fix here:
//  (a) WA/WB ping-pong at ROW granularity (3 taps / 18 floats per set):
//      step s loads row-step s+1 while computing row-step s. Loop-carried
//      across a cl-unroll-by-2 body -> static indexing, no scratch.
//  (b) sched_group_barrier(VMEM_READ, 6) after each load group pins the
//      loads at the top of the step (scheduler cannot sink them; DS/VALU
//      still free to move).
//  (c) __launch_bounds__(512,3) relaxes the VGPR cap to ~168 so both
//      weight sets + acc stay live without spill. Effective occupancy was
//      already ~3.1 waves/SIMD, so the ceiling cut is free.
// Weight table [cc][tap][oc][8] (coalesced 1KB wave loads); per-row anchor
// at middle tap keeps all 6 loads within signed-13-bit imm offsets.

typedef float v2f __attribute__((ext_vector_type(2)));

#define B_    4
#define CIN_  32
#define COUT_ 32
#define H_    128
#define W_    128
#define HW_   (H_ * W_)
#define OUTSZ_ (B_ * COUT_ * H_ * W_)

// tab layout: [cc][tap][oc][8] = {C,S,w0,w1,w2,w3,0,0}; 294912 B
__global__ __launch_bounds__(256)
void build_wtab(const float* __restrict__ w, const float* __restrict__ wr,
                float* __restrict__ tab)
{
    int idx = blockIdx.x * 256 + threadIdx.x;   // ((cc*9+tap)<<5)|oc
    if (idx >= CIN_ * 9 * COUT_) return;        // 9216
    int oc  = idx & 31;
    int t2  = idx >> 5;
    int tap = t2 % 9;
    int cc  = t2 / 9;
    int i = tap / 3, j = tap - i * 3;
    int base = (oc * CIN_ + cc) * 9;
    float w0 = w[base + i * 3 + j];
    float w1 = w[base + (2 - j) * 3 + i];
    float w2 = w[base + (2 - i) * 3 + (2 - j)];
    float w3 = w[base + j * 3 + (2 - i)];
    float S, C;
    sincosf(wr[base + i * 3 + j], &S, &C);
    float* dst = tab + (size_t)idx * 8;
    dst[0] = C;  dst[1] = S;
    dst[2] = w0; dst[3] = w1;
    dst[4] = w2; dst[5] = w3;
    dst[6] = 0.0f; dst[7] = 0.0f;
}

#define NC_    8                      // channels staged per barrier-pair
#define NG_    (CIN_ / NC_)           // 4 groups
#define ROWF_  68                     // floats per row = 34 pairs x 2
#define CLSTR_ (3 * ROWF_)            // 204 floats per staged channel
#define USED_  (NC_ * CLSTR_)         // 1632 slots per plane
#define PLANE_ 1636                   // plane stride (pad; 1636%32=4)

struct WRow { float4 a0, a1, a2; float2 b0, b1, b2; };   // 18 floats

// Load one row-step's 6 weight words (taps 3r..3r+2) and pin them with a
// sched_group_barrier so they cannot be sunk into the compute below.
// Anchor = middle tap of the row; +-1024 B imm offsets for neighbors.
#define LOAD_WROW(Wd) do {                                                  \
    const float* _wp = wanchor + soff;                                      \
    (Wd).a0 = *reinterpret_cast<const float4*>(_wp - 256);                  \
    (Wd).b0 = *reinterpret_cast<const float2*>(_wp - 252);                  \
    (Wd).a1 = *reinterpret_cast<const float4*>(_wp);                        \
    (Wd).b1 = *reinterpret_cast<const float2*>(_wp + 4);                    \
    (Wd).a2 = *reinterpret_cast<const float4*>(_wp + 256);                  \
    (Wd).b2 = *reinterpret_cast<const float2*>(_wp + 260);                  \
    soff += 768;                                                            \
    soff = (soff < 72960) ? soff : 72960;  /* clamp final dead prefetch */  \
    __builtin_amdgcn_sched_group_barrier(0x020, 6, 0); /* 6 VMEM reads */   \
} while (0)

#define CORE_TAP(W4, W2, JJ) do {                                           \
    v2f _C2  = {(W4).x, (W4).x};                                            \
    v2f _S2  = {(W4).y, (W4).y};                                            \
    v2f _w0  = {(W4).z, (W4).z};                                            \
    v2f _w1  = {(W4).w, (W4).w};                                            \
    v2f _w2  = {(W2).x, (W2).x};                                            \
    v2f _w3  = {(W2).y, (W2).y};                                            \
    _Pragma("unroll")                                                       \
    for (int _q = 0; _q < 2; ++_q) {                                        \
        v2f _f  = _fP[_q + (JJ)];                                           \
        v2f _r0 = _aP[_q + (JJ)];                                           \
        v2f _r1 = _bP[_q + (JJ)];                                           \
        v2f _m1 = _S2 * _r1;                                                \
        v2f _u  = __builtin_elementwise_fma(_C2, _r0, _m1);                 \
        v2f _m2 = _S2 * _r0;                                                \
        v2f _vv = __builtin_elementwise_fma(_C2, _r1, -_m2);                \
        v2f _g0 = __builtin_elementwise_max(_u,  (v2f)(0.0f));              \
        v2f _g1 = __builtin_elementwise_max(_vv, (v2f)(0.0f));              \
        v2f _t0 = _f * _g0;                                                 \
        v2f _t1 = _f * _g1;                                                 \
        v2f _t2 = __builtin_elementwise_fma(_f, -_u,  _t0);                 \
        v2f _t3 = __builtin_elementwise_fma(_f, -_vv, _t1);                 \
        acc[_q][0] = __builtin_elementwise_fma(_t0, _w0, acc[_q][0]);       \
        acc[_q][1] = __builtin_elementwise_fma(_t1, _w1, acc[_q][1]);       \
        acc[_q][2] = __builtin_elementwise_fma(_t2, _w2, acc[_q][2]);       \
        acc[_q][3] = __builtin_elementwise_fma(_t3, _w3, acc[_q][3]);       \
    }                                                                       \
} while (0)

#define COMPUTE_ROW(Wr, CL, II) do {                                        \
    const int _bi = (CL) * CLSTR_ + (II) * ROWF_ + (p << 1);                \
    float4 _fA = *reinterpret_cast<const float4*>(&sm[_bi]);                \
    float4 _fB = *reinterpret_cast<const float4*>(&sm[_bi + 4]);            \
    float4 _aA = *reinterpret_cast<const float4*>(&sm[PLANE_ + _bi]);       \
    float4 _aB = *reinterpret_cast<const float4*>(&sm[PLANE_ + _bi + 4]);   \
    float4 _bA = *reinterpret_cast<const float4*>(&sm[2 * PLANE_ + _bi]);   \
    float4 _bB = *reinterpret_cast<const float4*>(&sm[2 * PLANE_ + _bi + 4]);\
    v2f _fP[4] = {{_fA.x,_fA.y},{_fA.z,_fA.w},{_fB.x,_fB.y},{_fB.z,_fB.w}}; \
    v2f _aP[4] = {{_aA.x,_aA.y},{_aA.z,_aA.w},{_aB.x,_aB.y},{_aB.z,_aB.w}}; \
    v2f _bP[4] = {{_bA.x,_bA.y},{_bA.z,_bA.w},{_bB.x,_bB.y},{_bB.z,_bB.w}}; \
    CORE_TAP((Wr).a0, (Wr).b0, 0);                                          \
    CORE_TAP((Wr).a1, (Wr).b1, 1);                                          \
    CORE_TAP((Wr).a2, (Wr).b2, 2);                                          \
} while (0)

#define STEP(WLD, WUSE, CL, II) do {                                        \
    LOAD_WROW(WLD);                                                         \
    COMPUTE_ROW(WUSE, CL, II);                                              \
} while (0)

__global__ __launch_bounds__(512, 3)
void orient_conv_kernel(const float* __restrict__ f,
                        const float* __restrict__ r0,
                        const float* __restrict__ r1,
                        const float* __restrict__ tab,
                        float* __restrict__ out)
{
    // planes: 0=f, PLANE_=r0, 2*PLANE_=r1. Within plane:
    // [cl(8)][row(3)][pairslot(68)] ; pairslot = c01*2 + s holds col c01+32*s
    __shared__ float sm[3 * PLANE_];   // 19632 B

    const int tid   = threadIdx.x;
    const int oc    = tid & 31;
    const int pxg   = tid >> 5;            // 0..15
    const int p     = pxg << 1;            // even pair index 0..30
    const int bid   = blockIdx.x;          // 0..1023
    const int b     = bid >> 8;
    const int rem   = bid & 255;
    const int h     = rem >> 1;
    const int wbase = (rem & 1) << 6;      // 0 or 64

    // ---- staging descriptors: rounds 0..2 always valid, round 3 tid<96 ----
    int      goff[4], sidx[4];
    unsigned msk[4];
#pragma unroll
    for (int k = 0; k < 4; ++k) {
        int s = tid + (k << 9);
        if (s < USED_) {
            int cl  = s / CLSTR_;
            int r2  = s - cl * CLSTR_;
            int row = r2 / ROWF_;
            int q2  = r2 - row * ROWF_;     // 0..67
            int col = (q2 >> 1) + ((q2 & 1) << 5);   // c01 + 32*s -> 0..65
            int gh = h + row - 1;
            int gw = wbase + col - 1;
            bool ok = ((unsigned)gh < (unsigned)H_) & ((unsigned)gw < (unsigned)W_);
            goff[k] = ok ? (cl * HW_ + gh * W_ + gw) : 0;
            msk[k]  = ok ? 0xFFFFFFFFu : 0u;
            sidx[k] = s;
        } else { goff[k] = 0; msk[k] = 0u; sidx[k] = USED_; }  // pad slot
    }
    const bool have3 = (tid + 1536) < USED_;   // tid < 96
    const int chanBase = b * (CIN_ * HW_);

    v2f acc[2][4];                     // [pair q][orient]; elems = px, px+32
#pragma unroll
    for (int q = 0; q < 2; ++q)
#pragma unroll
        for (int o = 0; o < 4; ++o) acc[q][o] = (v2f)(0.0f);

    // ---- weight row-step pipeline state ----
    // row-step s = cc*3 + r, s in [0,95]; anchor = tap (3r+1) of cc.
    // element offset = ((3s+1)*32 + oc)*8 = s*768 + 256 + 8*oc.
    const float* wanchor = tab + (size_t)((1 << 5) | oc) * 8;  // s=0 anchor
    int soff = 0;
    WRow WA, WB;
    LOAD_WROW(WA);                     // prologue: row-step 0 -> WA

    // ---- prefetch group 0 ----
    float tF[4], tA[4], tB[4];
    {
        const float* fb = f  + chanBase;
        const float* ab = r0 + chanBase;
        const float* bb = r1 + chanBase;
#pragma unroll
        for (int k = 0; k < 3; ++k) {
            tF[k] = fb[goff[k]]; tA[k] = ab[goff[k]]; tB[k] = bb[goff[k]];
        }
        if (have3) { tF[3] = fb[goff[3]]; tA[3] = ab[goff[3]]; tB[3] = bb[goff[3]]; }
    }

#pragma unroll 1
    for (int g = 0; g < NG_; ++g) {
        __syncthreads();   // all waves done reading LDS of group g-1
#pragma unroll
        for (int k = 0; k < 3; ++k) {
            sm[             sidx[k]] = __uint_as_float(__float_as_uint(tF[k]) & msk[k]);
            sm[PLANE_     + sidx[k]] = __uint_as_float(__float_as_uint(tA[k]) & msk[k]);
            sm[2 * PLANE_ + sidx[k]] = __uint_as_float(__float_as_uint(tB[k]) & msk[k]);
        }
        if (have3) {
            sm[             sidx[3]] = __uint_as_float(__float_as_uint(tF[3]) & msk[3]);
            sm[PLANE_     + sidx[3]] = __uint_as_float(__float_as_uint(tA[3]) & msk[3]);
            sm[2 * PLANE_ + sidx[3]] = __uint_as_float(__float_as_uint(tB[3]) & msk[3]);
        }
        __syncthreads();

        // ---- prefetch group g+1 (in flight during compute below) ----
        if (g + 1 < NG_) {
            const int gb = chanBase + (g + 1) * (NC_ * HW_);
            const float* fb = f  + gb;
            const float* ab = r0 + gb;
            const float* bb = r1 + gb;
#pragma unroll
            for (int k = 0; k < 3; ++k) {
                tF[k] = fb[goff[k]]; tA[k] = ab[goff[k]]; tB[k] = bb[goff[k]];
            }
            if (have3) { tF[3] = fb[goff[3]]; tA[3] = ab[goff[3]]; tB[3] = bb[goff[3]]; }
        }

        // ---- compute the NC_ staged channels, 2 per iteration ----
        // 6 row-steps per iteration; compute step s uses weights loaded at
        // the previous step's prefetch (one full row-compute of slack).
#pragma unroll 1
        for (int cl = 0; cl < NC_; cl += 2) {
            STEP(WB, WA, cl,     0);
            STEP(WA, WB, cl,     1);
            STEP(WB, WA, cl,     2);
            STEP(WA, WB, cl + 1, 0);
            STEP(WB, WA, cl + 1, 1);
            STEP(WA, WB, cl + 1, 2);
        }
    }

    // ---- epilogue: max/argmax over orientations (first-max tie-break) ----
    const float cosv[4] = {1.0f, -4.37113883e-08f, -1.0f, 1.19248806e-08f};
    const float sinv[4] = {0.0f, 1.0f, -8.74227766e-08f, -1.0f};
#pragma unroll
    for (int q = 0; q < 2; ++q) {
#pragma unroll
        for (int k = 0; k < 2; ++k) {
            int wcol = wbase + p + q + (k << 5);
            float a0 = acc[q][0][k], a1 = acc[q][1][k];
            float a2 = acc[q][2][k], a3 = acc[q][3][k];
            float best = a0; int bi = 0;
            if (a1 > best) { best = a1; bi = 1; }
            if (a2 > best) { best = a2; bi = 2; }
            if (a3 > best) { best = a3; bi = 3; }
            size_t o = ((size_t)(b * COUT_ + oc) * H_ + h) * W_ + wcol;
            out[o]              = best;
            out[o + OUTSZ_]     = cosv[bi];
            out[o + 2 * OUTSZ_] = sinv[bi];
        }
    }
}

extern "C" void kernel_launch(void* const* d_in, const int* in_sizes, int n_in,
                              void* d_out, int out_size, void* d_ws, size_t ws_size,
                              hipStream_t stream)
{
    const float* f  = (const float*)d_in[0];
    const float* r0 = (const float*)d_in[1];
    const float* r1 = (const float*)d_in[2];
    const float* w  = (const float*)d_in[3];
    const float* wr = (const float*)d_in[4];
    float* out = (float*)d_out;
    float* tab = (float*)d_ws;    // 294912 B

    build_wtab<<<dim3(36), dim3(256), 0, stream>>>(w, wr, tab);
    orient_conv_kernel<<<dim3(B_ * H_ * 2), dim3(512), 0, stream>>>(
        f, r0, r1, tab, out);
}

// Round 3
// 265.779 us; speedup vs baseline: 1.0922x; 1.0171x over previous
//
#include <hip/hip_runtime.h>

// Orient_Conv: 3x3 orientation-gated conv, 4 orientations + per-pixel argmax.
// B=4, CIN=COUT=32, H=W=128, pad=1.
//
// Gate identity (C=cos(wr), S=sin(wr), r0=cos(th), r1=sin(th)):
//   u = C*r0+S*r1, vv = C*r1-S*r0
//   gates: o0=relu(u), o1=relu(vv), o2=relu(-u), o3=relu(-vv)
//   products: t0=f*relu(u), t1=f*relu(vv), t2 = t0 - f*u (=f*relu(-u)),
//             t3 = t1 - f*vv  -> 14-op packed core, 2 px/v2f.
// Rotated weights at tap (i,j): w0=w[i][j], w1=w[2-j][i], w2=w[2-i][2-j],
//   w3=w[j][2-i].
//
// R13 = R12 + double-buffered LDS (one barrier per group, 8 -> 4 barriers)
// + XCD-aware block swizzle. R12 post-mortem: weight pipeline landed
// (VGPR 60, loads pinned) but only 222->216; VALU-busy = 75% x 216 =
// 162 us at ~78 TF during-busy = the achievable fp32 issue rate -> the
// remaining lever is the 25% NON-busy time. All 4 resident blocks/CU run
// identical code in convoy, so the 8 per-block __syncthreads drains are
// not covered by other blocks. Double-buffering removes the pre-write
// barrier (writers of buf[(g+1)&1] never race readers of buf[g&1]);
// proof: before wave W writes buf X at group g+2 it passed the barrier
// after write(g+1), which every wave reaches only after compute(g) (the
// readers of buf X). Staging loads for g+2 stay in flight across a full
// compute phase. XCD swizzle (bijective, nwg=1024 % 8 == 0) puts
// adjacent-h blocks (which share 2 of 3 halo rows) on the same XCD L2:
// currently h+-1 are 2 XCDs apart -> every input row fetched ~3x from HBM
// (FETCH 57 MB vs 24 MB ideal).

typedef float v2f __attribute__((ext_vector_type(2)));

#define B_    4
#define CIN_  32
#define COUT_ 32
#define H_    128
#define W_    128
#define HW_   (H_ * W_)
#define OUTSZ_ (B_ * COUT_ * H_ * W_)

// tab layout: [cc][tap][oc][8] = {C,S,w0,w1,w2,w3,0,0}; 294912 B
__global__ __launch_bounds__(256)
void build_wtab(const float* __restrict__ w, const float* __restrict__ wr,
                float* __restrict__ tab)
{
    int idx = blockIdx.x * 256 + threadIdx.x;   // ((cc*9+tap)<<5)|oc
    if (idx >= CIN_ * 9 * COUT_) return;        // 9216
    int oc  = idx & 31;
    int t2  = idx >> 5;
    int tap = t2 % 9;
    int cc  = t2 / 9;
    int i = tap / 3, j = tap - i * 3;
    int base = (oc * CIN_ + cc) * 9;
    float w0 = w[base + i * 3 + j];
    float w1 = w[base + (2 - j) * 3 + i];
    float w2 = w[base + (2 - i) * 3 + (2 - j)];
    float w3 = w[base + j * 3 + (2 - i)];
    float S, C;
    sincosf(wr[base + i * 3 + j], &S, &C);
    float* dst = tab + (size_t)idx * 8;
    dst[0] = C;  dst[1] = S;
    dst[2] = w0; dst[3] = w1;
    dst[4] = w2; dst[5] = w3;
    dst[6] = 0.0f; dst[7] = 0.0f;
}

#define NC_    8                      // channels staged per buffer
#define NG_    (CIN_ / NC_)           // 4 groups
#define ROWF_  68                     // floats per row = 34 pairs x 2
#define CLSTR_ (3 * ROWF_)            // 204 floats per staged channel
#define USED_  (NC_ * CLSTR_)         // 1632 slots per plane
#define PLANE_ 1636                   // plane stride (pad; 1636%32=4)
#define NBUF_  (3 * PLANE_)           // floats per buffer (f,r0,r1 planes)

struct WRow { float4 a0, a1, a2; float2 b0, b1, b2; };   // 18 floats

// Load one row-step's 6 weight words (taps 3r..3r+2) and pin them with a
// sched_group_barrier so they cannot be sunk into the compute below.
// Anchor = middle tap of the row; +-1024 B imm offsets for neighbors.
#define LOAD_WROW(Wd) do {                                                  \
    const float* _wp = wanchor + soff;                                      \
    (Wd).a0 = *reinterpret_cast<const float4*>(_wp - 256);                  \
    (Wd).b0 = *reinterpret_cast<const float2*>(_wp - 252);                  \
    (Wd).a1 = *reinterpret_cast<const float4*>(_wp);                        \
    (Wd).b1 = *reinterpret_cast<const float2*>(_wp + 4);                    \
    (Wd).a2 = *reinterpret_cast<const float4*>(_wp + 256);                  \
    (Wd).b2 = *reinterpret_cast<const float2*>(_wp + 260);                  \
    soff += 768;                                                            \
    soff = (soff < 72960) ? soff : 72960;  /* clamp final dead prefetch */  \
    __builtin_amdgcn_sched_group_barrier(0x020, 6, 0); /* 6 VMEM reads */   \
} while (0)

#define CORE_TAP(W4, W2, JJ) do {                                           \
    v2f _C2  = {(W4).x, (W4).x};                                            \
    v2f _S2  = {(W4).y, (W4).y};                                            \
    v2f _w0  = {(W4).z, (W4).z};                                            \
    v2f _w1  = {(W4).w, (W4).w};                                            \
    v2f _w2  = {(W2).x, (W2).x};                                            \
    v2f _w3  = {(W2).y, (W2).y};                                            \
    _Pragma("unroll")                                                       \
    for (int _q = 0; _q < 2; ++_q) {                                        \
        v2f _f  = _fP[_q + (JJ)];                                           \
        v2f _r0 = _aP[_q + (JJ)];                                           \
        v2f _r1 = _bP[_q + (JJ)];                                           \
        v2f _m1 = _S2 * _r1;                                                \
        v2f _u  = __builtin_elementwise_fma(_C2, _r0, _m1);                 \
        v2f _m2 = _S2 * _r0;                                                \
        v2f _vv = __builtin_elementwise_fma(_C2, _r1, -_m2);                \
        v2f _g0 = __builtin_elementwise_max(_u,  (v2f)(0.0f));              \
        v2f _g1 = __builtin_elementwise_max(_vv, (v2f)(0.0f));              \
        v2f _t0 = _f * _g0;                                                 \
        v2f _t1 = _f * _g1;                                                 \
        v2f _t2 = __builtin_elementwise_fma(_f, -_u,  _t0);                 \
        v2f _t3 = __builtin_elementwise_fma(_f, -_vv, _t1);                 \
        acc[_q][0] = __builtin_elementwise_fma(_t0, _w0, acc[_q][0]);       \
        acc[_q][1] = __builtin_elementwise_fma(_t1, _w1, acc[_q][1]);       \
        acc[_q][2] = __builtin_elementwise_fma(_t2, _w2, acc[_q][2]);       \
        acc[_q][3] = __builtin_elementwise_fma(_t3, _w3, acc[_q][3]);       \
    }                                                                       \
} while (0)

#define COMPUTE_ROW(Wr, RB, CL, II) do {                                    \
    const float* _rb = (RB);                                                \
    const int _bi = (CL) * CLSTR_ + (II) * ROWF_ + (p << 1);                \
    float4 _fA = *reinterpret_cast<const float4*>(&_rb[_bi]);               \
    float4 _fB = *reinterpret_cast<const float4*>(&_rb[_bi + 4]);           \
    float4 _aA = *reinterpret_cast<const float4*>(&_rb[PLANE_ + _bi]);      \
    float4 _aB = *reinterpret_cast<const float4*>(&_rb[PLANE_ + _bi + 4]);  \
    float4 _bA = *reinterpret_cast<const float4*>(&_rb[2 * PLANE_ + _bi]);  \
    float4 _bB = *reinterpret_cast<const float4*>(&_rb[2 * PLANE_ + _bi + 4]);\
    v2f _fP[4] = {{_fA.x,_fA.y},{_fA.z,_fA.w},{_fB.x,_fB.y},{_fB.z,_fB.w}}; \
    v2f _aP[4] = {{_aA.x,_aA.y},{_aA.z,_aA.w},{_aB.x,_aB.y},{_aB.z,_aB.w}}; \
    v2f _bP[4] = {{_bA.x,_bA.y},{_bA.z,_bA.w},{_bB.x,_bB.y},{_bB.z,_bB.w}}; \
    CORE_TAP((Wr).a0, (Wr).b0, 0);                                          \
    CORE_TAP((Wr).a1, (Wr).b1, 1);                                          \
    CORE_TAP((Wr).a2, (Wr).b2, 2);                                          \
} while (0)

#define STEP(WLD, WUSE, RB, CL, II) do {                                    \
    LOAD_WROW(WLD);                                                         \
    COMPUTE_ROW(WUSE, RB, CL, II);                                          \
} while (0)

// Issue the 12 global loads for group GI into tF/tA/tB (in flight across a
// full compute phase before STAGE_WRITE consumes them).
#define STAGE_LOAD(GI) do {                                                 \
    const int _gb = chanBase + (GI) * (NC_ * HW_);                          \
    const float* _fb = f  + _gb;                                            \
    const float* _ab = r0 + _gb;                                            \
    const float* _bb = r1 + _gb;                                            \
    _Pragma("unroll")                                                       \
    for (int _k = 0; _k < 3; ++_k) {                                        \
        tF[_k] = _fb[goff[_k]]; tA[_k] = _ab[goff[_k]]; tB[_k] = _bb[goff[_k]]; \
    }                                                                       \
    if (have3) { tF[3] = _fb[goff[3]]; tA[3] = _ab[goff[3]]; tB[3] = _bb[goff[3]]; } \
} while (0)

#define STAGE_WRITE(DST) do {                                               \
    float* _d = (DST);                                                      \
    _Pragma("unroll")                                                       \
    for (int _k = 0; _k < 3; ++_k) {                                        \
        _d[             sidx[_k]] = __uint_as_float(__float_as_uint(tF[_k]) & msk[_k]); \
        _d[PLANE_     + sidx[_k]] = __uint_as_float(__float_as_uint(tA[_k]) & msk[_k]); \
        _d[2 * PLANE_ + sidx[_k]] = __uint_as_float(__float_as_uint(tB[_k]) & msk[_k]); \
    }                                                                       \
    if (have3) {                                                            \
        _d[             sidx[3]] = __uint_as_float(__float_as_uint(tF[3]) & msk[3]); \
        _d[PLANE_     + sidx[3]] = __uint_as_float(__float_as_uint(tA[3]) & msk[3]); \
        _d[2 * PLANE_ + sidx[3]] = __uint_as_float(__float_as_uint(tB[3]) & msk[3]); \
    }                                                                       \
} while (0)

__global__ __launch_bounds__(512, 3)
void orient_conv_kernel(const float* __restrict__ f,
                        const float* __restrict__ r0,
                        const float* __restrict__ r1,
                        const float* __restrict__ tab,
                        float* __restrict__ out)
{
    // Double-buffered: sm[buf][plane][slot]; planes 0=f, 1=r0, 2=r1.
    // Within plane: [cl(8)][row(3)][pairslot(68)]; pairslot = c01*2 + s
    // holds col c01+32*s.
    __shared__ float sm[2 * NBUF_];    // 39264 B; 4 blocks/CU = 157 KB

    const int tid   = threadIdx.x;
    const int oc    = tid & 31;
    const int pxg   = tid >> 5;            // 0..15
    const int p     = pxg << 1;            // even pair index 0..30
    // XCD-aware bijective swizzle: 8 XCDs, nwg=1024, 1024%8==0.
    // XCD x gets a contiguous 128-block logical range -> adjacent-h blocks
    // (sharing 2 of 3 halo rows) hit the same XCD L2.
    const int obid  = blockIdx.x;
    const int bid   = (obid & 7) * ((B_ * H_ * 2) >> 3) + (obid >> 3);
    const int b     = bid >> 8;
    const int rem   = bid & 255;
    const int h     = rem >> 1;
    const int wbase = (rem & 1) << 6;      // 0 or 64

    // ---- staging descriptors: rounds 0..2 always valid, round 3 tid<96 ----
    int      goff[4], sidx[4];
    unsigned msk[4];
#pragma unroll
    for (int k = 0; k < 4; ++k) {
        int s = tid + (k << 9);
        if (s < USED_) {
            int cl  = s / CLSTR_;
            int r2  = s - cl * CLSTR_;
            int row = r2 / ROWF_;
            int q2  = r2 - row * ROWF_;     // 0..67
            int col = (q2 >> 1) + ((q2 & 1) << 5);   // c01 + 32*s -> 0..65
            int gh = h + row - 1;
            int gw = wbase + col - 1;
            bool ok = ((unsigned)gh < (unsigned)H_) & ((unsigned)gw < (unsigned)W_);
            goff[k] = ok ? (cl * HW_ + gh * W_ + gw) : 0;
            msk[k]  = ok ? 0xFFFFFFFFu : 0u;
            sidx[k] = s;
        } else { goff[k] = 0; msk[k] = 0u; sidx[k] = USED_; }  // pad slot
    }
    const bool have3 = (tid + 1536) < USED_;   // tid < 96
    const int chanBase = b * (CIN_ * HW_);

    v2f acc[2][4];                     // [pair q][orient]; elems = px, px+32
#pragma unroll
    for (int q = 0; q < 2; ++q)
#pragma unroll
        for (int o = 0; o < 4; ++o) acc[q][o] = (v2f)(0.0f);

    // ---- weight row-step pipeline state ----
    // row-step s = cc*3 + r, s in [0,95]; anchor = tap (3r+1) of cc.
    // element offset = ((3s+1)*32 + oc)*8 = s*768 + 256 + 8*oc.
    const float* wanchor = tab + (size_t)((1 << 5) | oc) * 8;  // s=0 anchor
    int soff = 0;
    WRow WA, WB;
    LOAD_WROW(WA);                     // prologue: row-step 0 -> WA

    // ---- prologue staging: g0 -> buf0; g1 loads in flight ----
    float tF[4], tA[4], tB[4];
    STAGE_LOAD(0);
    STAGE_WRITE(sm);                   // vmcnt covered by data dependence
    STAGE_LOAD(1);
    __syncthreads();

#pragma unroll 1
    for (int g = 0; g < NG_; ++g) {
        const float* rb = sm + (g & 1) * NBUF_;

        // ---- compute the NC_ staged channels, 2 per iteration ----
        // 6 row-steps per iteration; compute step s uses weights loaded at
        // the previous step's prefetch (one full row-compute of slack).
#pragma unroll 1
        for (int cl = 0; cl < NC_; cl += 2) {
            STEP(WB, WA, rb, cl,     0);
            STEP(WA, WB, rb, cl,     1);
            STEP(WB, WA, rb, cl,     2);
            STEP(WA, WB, rb, cl + 1, 0);
            STEP(WB, WA, rb, cl + 1, 1);
            STEP(WA, WB, rb, cl + 1, 2);
        }

        // ---- stage group g+1 into the other buffer, prefetch g+2 ----
        if (g + 1 < NG_) {
            float* wbuf = sm + ((g + 1) & 1) * NBUF_;
            STAGE_WRITE(wbuf);         // waits on loads issued one phase ago
            if (g + 2 < NG_) STAGE_LOAD(g + 2);
            __syncthreads();           // one barrier per group (4 total)
        }
    }

    // ---- epilogue: max/argmax over orientations (first-max tie-break) ----
    const float cosv[4] = {1.0f, -4.37113883e-08f, -1.0f, 1.19248806e-08f};
    const float sinv[4] = {0.0f, 1.0f, -8.74227766e-08f, -1.0f};
#pragma unroll
    for (int q = 0; q < 2; ++q) {
#pragma unroll
        for (int k = 0; k < 2; ++k) {
            int wcol = wbase + p + q + (k << 5);
            float a0 = acc[q][0][k], a1 = acc[q][1][k];
            float a2 = acc[q][2][k], a3 = acc[q][3][k];
            float best = a0; int bi = 0;
            if (a1 > best) { best = a1; bi = 1; }
            if (a2 > best) { best = a2; bi = 2; }
            if (a3 > best) { best = a3; bi = 3; }
            size_t o = ((size_t)(b * COUT_ + oc) * H_ + h) * W_ + wcol;
            out[o]              = best;
            out[o + OUTSZ_]     = cosv[bi];
            out[o + 2 * OUTSZ_] = sinv[bi];
        }
    }
}

extern "C" void kernel_launch(void* const* d_in, const int* in_sizes, int n_in,
                              void* d_out, int out_size, void* d_ws, size_t ws_size,
                              hipStream_t stream)
{
    const float* f  = (const float*)d_in[0];
    const float* r0 = (const float*)d_in[1];
    const float* r1 = (const float*)d_in[2];
    const float* w  = (const float*)d_in[3];
    const float* wr = (const float*)d_in[4];
    float* out = (float*)d_out;
    float* tab = (float*)d_ws;    // 294912 B

    build_wtab<<<dim3(36), dim3(256), 0, stream>>>(w, wr, tab);
    orient_conv_kernel<<<dim3(B_ * H_ * 2), dim3(512), 0, stream>>>(
        f, r0, r1, tab, out);
}